// Round 1
// baseline (641.794 us; speedup 1.0000x reference)
//
#include <hip/hip_runtime.h>

#define N_NODES 50000
#define N_EDGES 800000
#define DIM 128
#define N_GRAPHS 64
#define NTILES 3125  // N_NODES / 16

typedef __attribute__((ext_vector_type(8))) short short8;
typedef __attribute__((ext_vector_type(4))) float f32x4;

__device__ __forceinline__ float bf2f(unsigned short h) {
  unsigned int u = ((unsigned int)h) << 16;
  return __builtin_bit_cast(float, u);
}
__device__ __forceinline__ unsigned short f2bf(float f) {
  unsigned int u = __builtin_bit_cast(unsigned int, f);
  u += 0x7FFFu + ((u >> 16) & 1u);
  return (unsigned short)(u >> 16);
}

// ---------------- prep kernels ----------------

__global__ void k_zero(int* deg, int* gcnt, float* out) {
  int i = blockIdx.x * 256 + threadIdx.x;
  if (i < N_NODES) deg[i] = 0;
  if (i < N_GRAPHS) gcnt[i] = 0;
  if (i < N_GRAPHS * DIM) out[i] = 0.f;
}

__global__ void k_deg(const int* __restrict__ ei, int* __restrict__ deg) {
  int e = blockIdx.x * 256 + threadIdx.x;
  if (e >= N_EDGES) return;
  atomicAdd(&deg[ei[N_EDGES + e]], 1);
}

__global__ void k_scan(const int* __restrict__ deg, int* __restrict__ rowptr,
                       int* __restrict__ wofs) {
  __shared__ int sums[256];
  int tid = threadIdx.x;
  const int CH = (N_NODES + 255) / 256;  // 196
  int base = tid * CH;
  int s = 0;
  for (int i = 0; i < CH; ++i) {
    int idx = base + i;
    if (idx < N_NODES) s += deg[idx];
  }
  sums[tid] = s;
  __syncthreads();
  for (int off = 1; off < 256; off <<= 1) {
    int v = (tid >= off) ? sums[tid - off] : 0;
    __syncthreads();
    sums[tid] += v;
    __syncthreads();
  }
  int run = (tid == 0) ? 0 : sums[tid - 1];
  for (int i = 0; i < CH; ++i) {
    int idx = base + i;
    if (idx < N_NODES) {
      rowptr[idx] = run;
      wofs[idx] = run;
      run += deg[idx];
    }
  }
  if (tid == 255) rowptr[N_NODES] = run;  // == N_EDGES
}

__global__ void k_scatter(const int* __restrict__ ei, int* __restrict__ wofs,
                          int* __restrict__ col) {
  int e = blockIdx.x * 256 + threadIdx.x;
  if (e >= N_EDGES) return;
  int d = ei[N_EDGES + e];
  int p = atomicAdd(&wofs[d], 1);
  col[p] = ei[e];  // src node id
}

__global__ void k_xbf(const float* __restrict__ x, unsigned short* __restrict__ xbf) {
  int i = blockIdx.x * 256 + threadIdx.x;  // one float4 per thread
  if (i * 4 >= N_NODES * DIM) return;
  float4 v = ((const float4*)x)[i];
  unsigned int lo = (unsigned int)f2bf(v.x) | ((unsigned int)f2bf(v.y) << 16);
  unsigned int hi = (unsigned int)f2bf(v.z) | ((unsigned int)f2bf(v.w) << 16);
  uint2 o; o.x = lo; o.y = hi;
  ((uint2*)xbf)[i] = o;
}

// Fragment-ordered transposed bf16 weights: wfrag[mat][t][kk][lane][j]
// holds W[k0+j][16t + (lane&15)] with k0 = 32*kk + 8*(lane>>4).
__global__ void k_wprep(const float* __restrict__ w0, const float* __restrict__ w1,
                        const float* __restrict__ w2, const float* __restrict__ w3,
                        const float* __restrict__ w4, const float* __restrict__ w5,
                        unsigned short* __restrict__ wfrag) {
  int idx = blockIdx.x * 256 + threadIdx.x;  // 6 * 2048
  if (idx >= 6 * 2048) return;
  int mat = idx >> 11;
  int rem = idx & 2047;
  int lane = rem & 63;
  int kk = (rem >> 6) & 3;
  int t = rem >> 8;
  const float* w = (mat == 0) ? w0 : (mat == 1) ? w1 : (mat == 2) ? w2
                 : (mat == 3) ? w3 : (mat == 4) ? w4 : w5;
  int row = t * 16 + (lane & 15);          // output column c
  int k0 = kk * 32 + (lane >> 4) * 8;
  unsigned int v[8];
  #pragma unroll
  for (int j = 0; j < 8; ++j) v[j] = f2bf(w[(k0 + j) * DIM + row]);
  uint4 o;
  o.x = v[0] | (v[1] << 16);
  o.y = v[2] | (v[3] << 16);
  o.z = v[4] | (v[5] << 16);
  o.w = v[6] | (v[7] << 16);
  ((uint4*)wfrag)[idx] = o;
}

__global__ void k_gcnt(const int* __restrict__ batch, int* __restrict__ gcnt) {
  int i = blockIdx.x * 256 + threadIdx.x;
  if (i >= N_NODES) return;
  atomicAdd(&gcnt[batch[i]], 1);
}

// ---------------- per-layer kernels ----------------

// one wave per node: mean over neighbor rows (bf16 in, f32 acc, bf16 out)
__global__ __launch_bounds__(256) void k_agg(const unsigned short* __restrict__ xin,
                                             const int* __restrict__ rowptr,
                                             const int* __restrict__ col,
                                             unsigned short* __restrict__ meanbf) {
  int wid = (blockIdx.x * blockDim.x + threadIdx.x) >> 6;
  int lane = threadIdx.x & 63;
  if (wid >= N_NODES) return;
  int start = rowptr[wid], end = rowptr[wid + 1];
  float a0 = 0.f, a1 = 0.f;
  for (int j0 = start; j0 < end; j0 += 64) {
    int m = end - j0;
    if (m > 64) m = 64;
    int idx = (lane < m) ? col[j0 + lane] : 0;
    int jj = 0;
    for (; jj + 4 <= m; jj += 4) {
      int s0 = __shfl(idx, jj + 0);
      int s1 = __shfl(idx, jj + 1);
      int s2 = __shfl(idx, jj + 2);
      int s3 = __shfl(idx, jj + 3);
      unsigned int v0 = *(const unsigned int*)(xin + (size_t)s0 * DIM + lane * 2);
      unsigned int v1 = *(const unsigned int*)(xin + (size_t)s1 * DIM + lane * 2);
      unsigned int v2 = *(const unsigned int*)(xin + (size_t)s2 * DIM + lane * 2);
      unsigned int v3 = *(const unsigned int*)(xin + (size_t)s3 * DIM + lane * 2);
      a0 += bf2f((unsigned short)(v0 & 0xffff)) + bf2f((unsigned short)(v1 & 0xffff))
          + bf2f((unsigned short)(v2 & 0xffff)) + bf2f((unsigned short)(v3 & 0xffff));
      a1 += bf2f((unsigned short)(v0 >> 16)) + bf2f((unsigned short)(v1 >> 16))
          + bf2f((unsigned short)(v2 >> 16)) + bf2f((unsigned short)(v3 >> 16));
    }
    for (; jj < m; ++jj) {
      int s = __shfl(idx, jj);
      unsigned int v = *(const unsigned int*)(xin + (size_t)s * DIM + lane * 2);
      a0 += bf2f((unsigned short)(v & 0xffff));
      a1 += bf2f((unsigned short)(v >> 16));
    }
  }
  int d = end - start;
  float sc = 1.0f / (float)(d > 1 ? d : 1);
  unsigned int o = (unsigned int)f2bf(a0 * sc) | ((unsigned int)f2bf(a1 * sc) << 16);
  *(unsigned int*)(meanbf + (size_t)wid * DIM + lane * 2) = o;
}

// fused: h = [relu](mean @ Wl + xin @ Wr + b) then row l2-normalize; bf16 out.
// one wave handles one 16-row tile, all 128 output cols.
__global__ __launch_bounds__(256) void k_gemm(const unsigned short* __restrict__ meanbf,
                                              const unsigned short* __restrict__ xin,
                                              const unsigned short* __restrict__ wfragL,
                                              const unsigned short* __restrict__ wfragR,
                                              const float* __restrict__ bias,
                                              unsigned short* __restrict__ outbf,
                                              int relu) {
  __shared__ __align__(16) unsigned short wl[8 * 4 * 64 * 8];  // 32 KB
  __shared__ __align__(16) unsigned short wr[8 * 4 * 64 * 8];  // 32 KB
  const int tid = threadIdx.x;
  {
    const uint4* gl = (const uint4*)wfragL;
    const uint4* gr = (const uint4*)wfragR;
    uint4* sl = (uint4*)wl;
    uint4* sr = (uint4*)wr;
    #pragma unroll
    for (int i = 0; i < 8; ++i) {  // 2048 uint4 per array / 256 threads
      sl[tid + 256 * i] = gl[tid + 256 * i];
      sr[tid + 256 * i] = gr[tid + 256 * i];
    }
  }
  __syncthreads();

  int wave = tid >> 6;
  int lane = tid & 63;
  int tb = blockIdx.x * 4 + wave;
  if (tb >= NTILES) return;

  int lg = lane >> 4;   // 0..3
  int li = lane & 15;   // 0..15

  // A fragments: lane holds row (tb*16+li), k = 32*kk + 8*lg + j (contiguous 16B)
  short8 am[4], ax[4];
  const unsigned short* mrow = meanbf + ((size_t)(tb * 16 + li)) * DIM + lg * 8;
  const unsigned short* xrow = xin + ((size_t)(tb * 16 + li)) * DIM + lg * 8;
  #pragma unroll
  for (int kk = 0; kk < 4; ++kk) {
    am[kk] = *(const short8*)(mrow + kk * 32);
    ax[kk] = *(const short8*)(xrow + kk * 32);
  }

  f32x4 acc[8];
  #pragma unroll
  for (int t = 0; t < 8; ++t) {
    f32x4 c = {0.f, 0.f, 0.f, 0.f};
    #pragma unroll
    for (int kk = 0; kk < 4; ++kk) {
      short8 bl = *(const short8*)(wl + (((t * 4 + kk) * 64 + lane) * 8));
      c = __builtin_amdgcn_mfma_f32_16x16x32_bf16(am[kk], bl, c, 0, 0, 0);
      short8 br = *(const short8*)(wr + (((t * 4 + kk) * 64 + lane) * 8));
      c = __builtin_amdgcn_mfma_f32_16x16x32_bf16(ax[kk], br, c, 0, 0, 0);
    }
    float bv = bias[t * 16 + li];
    #pragma unroll
    for (int r = 0; r < 4; ++r) {
      float v = c[r] + bv;
      if (relu) v = fmaxf(v, 0.f);
      c[r] = v;
    }
    acc[t] = c;
  }

  // l2 norm per output row: row = tb*16 + lg*4 + r; cols spread over t and li.
  float scale[4];
  #pragma unroll
  for (int r = 0; r < 4; ++r) {
    float s = 0.f;
    #pragma unroll
    for (int t = 0; t < 8; ++t) s += acc[t][r] * acc[t][r];
    s += __shfl_xor(s, 1);
    s += __shfl_xor(s, 2);
    s += __shfl_xor(s, 4);
    s += __shfl_xor(s, 8);
    float n = sqrtf(s);
    scale[r] = 1.0f / fmaxf(n, 1e-12f);
  }

  #pragma unroll
  for (int t = 0; t < 8; ++t) {
    #pragma unroll
    for (int r = 0; r < 4; ++r) {
      outbf[((size_t)(tb * 16 + lg * 4 + r)) * DIM + t * 16 + li] =
          f2bf(acc[t][r] * scale[r]);
    }
  }
}

// ---------------- pooling ----------------

__global__ void k_pool(const unsigned short* __restrict__ h,
                       const int* __restrict__ batch, float* __restrict__ out) {
  int c = threadIdx.x;  // 0..127
  int n0 = blockIdx.x * 128;
  int nend = n0 + 128;
  if (nend > N_NODES) nend = N_NODES;
  float acc = 0.f;
  int cur = batch[n0];
  for (int n = n0; n < nend; ++n) {
    int g = batch[n];
    if (g != cur) {
      atomicAdd(&out[cur * DIM + c], acc);
      acc = 0.f;
      cur = g;
    }
    acc += bf2f(h[(size_t)n * DIM + c]);
  }
  atomicAdd(&out[cur * DIM + c], acc);
}

__global__ void k_div(float* __restrict__ out, const int* __restrict__ gcnt) {
  int i = blockIdx.x * 128 + threadIdx.x;  // 8192
  int g = i >> 7;
  int cv = gcnt[g];
  out[i] = out[i] / (float)(cv > 1 ? cv : 1);
}

// ---------------- launch ----------------

extern "C" void kernel_launch(void* const* d_in, const int* in_sizes, int n_in,
                              void* d_out, int out_size, void* d_ws, size_t ws_size,
                              hipStream_t stream) {
  const float* x   = (const float*)d_in[0];
  const int* ei    = (const int*)d_in[1];
  const int* batch = (const int*)d_in[2];
  const float* Wl1 = (const float*)d_in[3];
  const float* Wr1 = (const float*)d_in[4];
  const float* b1  = (const float*)d_in[5];
  const float* Wl2 = (const float*)d_in[6];
  const float* Wr2 = (const float*)d_in[7];
  const float* b2  = (const float*)d_in[8];
  const float* Wl3 = (const float*)d_in[9];
  const float* Wr3 = (const float*)d_in[10];
  const float* b3  = (const float*)d_in[11];
  float* out = (float*)d_out;

  char* ws = (char*)d_ws;
  size_t off = 0;
  auto alloc = [&](size_t bytes) {
    void* p = ws + off;
    off += (bytes + 255) & ~(size_t)255;
    return p;
  };
  unsigned short* xbf   = (unsigned short*)alloc((size_t)N_NODES * DIM * 2);
  unsigned short* hB    = (unsigned short*)alloc((size_t)N_NODES * DIM * 2);
  unsigned short* hC    = (unsigned short*)alloc((size_t)N_NODES * DIM * 2);
  unsigned short* mean  = (unsigned short*)alloc((size_t)N_NODES * DIM * 2);
  unsigned short* wfrag = (unsigned short*)alloc((size_t)6 * 2048 * 16);
  int* deg    = (int*)alloc((size_t)N_NODES * 4);
  int* rowptr = (int*)alloc((size_t)(N_NODES + 1) * 4);
  int* wofs   = (int*)alloc((size_t)N_NODES * 4);
  int* col    = (int*)alloc((size_t)N_EDGES * 4);
  int* gcnt   = (int*)alloc((size_t)N_GRAPHS * 4);

  // prep
  k_zero<<<196, 256, 0, stream>>>(deg, gcnt, out);
  k_deg<<<3125, 256, 0, stream>>>(ei, deg);
  k_scan<<<1, 256, 0, stream>>>(deg, rowptr, wofs);
  k_scatter<<<3125, 256, 0, stream>>>(ei, wofs, col);
  k_xbf<<<6250, 256, 0, stream>>>(x, xbf);
  k_wprep<<<48, 256, 0, stream>>>(Wl1, Wr1, Wl2, Wr2, Wl3, Wr3, wfrag);
  k_gcnt<<<196, 256, 0, stream>>>(batch, gcnt);

  // layer 1
  k_agg<<<12500, 256, 0, stream>>>(xbf, rowptr, col, mean);
  k_gemm<<<782, 256, 0, stream>>>(mean, xbf, wfrag + 0 * 16384, wfrag + 1 * 16384, b1, hB, 1);
  // layer 2
  k_agg<<<12500, 256, 0, stream>>>(hB, rowptr, col, mean);
  k_gemm<<<782, 256, 0, stream>>>(mean, hB, wfrag + 2 * 16384, wfrag + 3 * 16384, b2, hC, 1);
  // layer 3
  k_agg<<<12500, 256, 0, stream>>>(hC, rowptr, col, mean);
  k_gemm<<<782, 256, 0, stream>>>(mean, hC, wfrag + 4 * 16384, wfrag + 5 * 16384, b3, hB, 0);

  // global mean pool
  k_pool<<<391, 128, 0, stream>>>(hB, batch, out);
  k_div<<<64, 128, 0, stream>>>(out, gcnt);
}

// Round 2
// 414.889 us; speedup vs baseline: 1.5469x; 1.5469x over previous
//
#include <hip/hip_runtime.h>

#define N_NODES 50000
#define N_EDGES 800000
#define DIM 128
#define N_GRAPHS 64
#define NTILES 3125  // N_NODES / 16

typedef __attribute__((ext_vector_type(8))) short short8;
typedef __attribute__((ext_vector_type(4))) float f32x4;

__device__ __forceinline__ float bf2f(unsigned short h) {
  unsigned int u = ((unsigned int)h) << 16;
  return __builtin_bit_cast(float, u);
}
__device__ __forceinline__ unsigned short f2bf(float f) {
  unsigned int u = __builtin_bit_cast(unsigned int, f);
  u += 0x7FFFu + ((u >> 16) & 1u);
  return (unsigned short)(u >> 16);
}

// ---------------- prep kernels ----------------

__global__ void k_zero(int* deg, float* out) {
  int i = blockIdx.x * 256 + threadIdx.x;
  if (i < N_NODES) deg[i] = 0;
  if (i < N_GRAPHS * DIM) out[i] = 0.f;
}

__global__ void k_deg(const int* __restrict__ ei, int* __restrict__ deg) {
  int e = blockIdx.x * 256 + threadIdx.x;
  if (e >= N_EDGES) return;
  atomicAdd(&deg[ei[N_EDGES + e]], 1);
}

__global__ void k_scan(const int* __restrict__ deg, int* __restrict__ rowptr,
                       int* __restrict__ wofs) {
  __shared__ int sums[256];
  int tid = threadIdx.x;
  const int CH = (N_NODES + 255) / 256;  // 196
  int base = tid * CH;
  int s = 0;
  for (int i = 0; i < CH; ++i) {
    int idx = base + i;
    if (idx < N_NODES) s += deg[idx];
  }
  sums[tid] = s;
  __syncthreads();
  for (int off = 1; off < 256; off <<= 1) {
    int v = (tid >= off) ? sums[tid - off] : 0;
    __syncthreads();
    sums[tid] += v;
    __syncthreads();
  }
  int run = (tid == 0) ? 0 : sums[tid - 1];
  for (int i = 0; i < CH; ++i) {
    int idx = base + i;
    if (idx < N_NODES) {
      rowptr[idx] = run;
      wofs[idx] = run;
      run += deg[idx];
    }
  }
  if (tid == 255) rowptr[N_NODES] = run;  // == N_EDGES
}

__global__ void k_scatter(const int* __restrict__ ei, int* __restrict__ wofs,
                          int* __restrict__ col) {
  int e = blockIdx.x * 256 + threadIdx.x;
  if (e >= N_EDGES) return;
  int d = ei[N_EDGES + e];
  int p = atomicAdd(&wofs[d], 1);
  col[p] = ei[e];  // src node id
}

__global__ void k_xbf(const float* __restrict__ x, unsigned short* __restrict__ xbf) {
  int i = blockIdx.x * 256 + threadIdx.x;  // one float4 per thread
  if (i * 4 >= N_NODES * DIM) return;
  float4 v = ((const float4*)x)[i];
  unsigned int lo = (unsigned int)f2bf(v.x) | ((unsigned int)f2bf(v.y) << 16);
  unsigned int hi = (unsigned int)f2bf(v.z) | ((unsigned int)f2bf(v.w) << 16);
  uint2 o; o.x = lo; o.y = hi;
  ((uint2*)xbf)[i] = o;
}

// Fragment-ordered transposed bf16 weights: wfrag[mat][t][kk][lane][j]
// holds W[k0+j][16t + (lane&15)] with k0 = 32*kk + 8*(lane>>4).
__global__ void k_wprep(const float* __restrict__ w0, const float* __restrict__ w1,
                        const float* __restrict__ w2, const float* __restrict__ w3,
                        const float* __restrict__ w4, const float* __restrict__ w5,
                        unsigned short* __restrict__ wfrag) {
  int idx = blockIdx.x * 256 + threadIdx.x;  // 6 * 2048
  if (idx >= 6 * 2048) return;
  int mat = idx >> 11;
  int rem = idx & 2047;
  int lane = rem & 63;
  int kk = (rem >> 6) & 3;
  int t = rem >> 8;
  const float* w = (mat == 0) ? w0 : (mat == 1) ? w1 : (mat == 2) ? w2
                 : (mat == 3) ? w3 : (mat == 4) ? w4 : w5;
  int row = t * 16 + (lane & 15);          // output column c
  int k0 = kk * 32 + (lane >> 4) * 8;
  unsigned int v[8];
  #pragma unroll
  for (int j = 0; j < 8; ++j) v[j] = f2bf(w[(k0 + j) * DIM + row]);
  uint4 o;
  o.x = v[0] | (v[1] << 16);
  o.y = v[2] | (v[3] << 16);
  o.z = v[4] | (v[5] << 16);
  o.w = v[6] | (v[7] << 16);
  ((uint4*)wfrag)[idx] = o;
}

// batch is sorted: gcnt[g] = lower_bound(g+1) - lower_bound(g). No atomics.
__global__ void k_gcnt(const int* __restrict__ batch, int* __restrict__ gcnt) {
  int g = threadIdx.x;  // 0..63
  if (g >= N_GRAPHS) return;
  int lo = 0, hi = N_NODES;
  while (lo < hi) { int mid = (lo + hi) >> 1; if (batch[mid] < g) lo = mid + 1; else hi = mid; }
  int s = lo;
  lo = 0; hi = N_NODES;
  int g1 = g + 1;
  while (lo < hi) { int mid = (lo + hi) >> 1; if (batch[mid] < g1) lo = mid + 1; else hi = mid; }
  gcnt[g] = lo - s;
}

// ---------------- per-layer kernels ----------------

// one wave per node: mean over neighbor rows (bf16 in, f32 acc, bf16 out)
__global__ __launch_bounds__(256) void k_agg(const unsigned short* __restrict__ xin,
                                             const int* __restrict__ rowptr,
                                             const int* __restrict__ col,
                                             unsigned short* __restrict__ meanbf) {
  int wid = (blockIdx.x * blockDim.x + threadIdx.x) >> 6;
  int lane = threadIdx.x & 63;
  if (wid >= N_NODES) return;
  int start = rowptr[wid], end = rowptr[wid + 1];
  float a0 = 0.f, a1 = 0.f;
  for (int j0 = start; j0 < end; j0 += 64) {
    int m = end - j0;
    if (m > 64) m = 64;
    int idx = (lane < m) ? col[j0 + lane] : 0;
    int jj = 0;
    for (; jj + 4 <= m; jj += 4) {
      int s0 = __shfl(idx, jj + 0);
      int s1 = __shfl(idx, jj + 1);
      int s2 = __shfl(idx, jj + 2);
      int s3 = __shfl(idx, jj + 3);
      unsigned int v0 = *(const unsigned int*)(xin + (size_t)s0 * DIM + lane * 2);
      unsigned int v1 = *(const unsigned int*)(xin + (size_t)s1 * DIM + lane * 2);
      unsigned int v2 = *(const unsigned int*)(xin + (size_t)s2 * DIM + lane * 2);
      unsigned int v3 = *(const unsigned int*)(xin + (size_t)s3 * DIM + lane * 2);
      a0 += bf2f((unsigned short)(v0 & 0xffff)) + bf2f((unsigned short)(v1 & 0xffff))
          + bf2f((unsigned short)(v2 & 0xffff)) + bf2f((unsigned short)(v3 & 0xffff));
      a1 += bf2f((unsigned short)(v0 >> 16)) + bf2f((unsigned short)(v1 >> 16))
          + bf2f((unsigned short)(v2 >> 16)) + bf2f((unsigned short)(v3 >> 16));
    }
    for (; jj < m; ++jj) {
      int s = __shfl(idx, jj);
      unsigned int v = *(const unsigned int*)(xin + (size_t)s * DIM + lane * 2);
      a0 += bf2f((unsigned short)(v & 0xffff));
      a1 += bf2f((unsigned short)(v >> 16));
    }
  }
  int d = end - start;
  float sc = 1.0f / (float)(d > 1 ? d : 1);
  unsigned int o = (unsigned int)f2bf(a0 * sc) | ((unsigned int)f2bf(a1 * sc) << 16);
  *(unsigned int*)(meanbf + (size_t)wid * DIM + lane * 2) = o;
}

// fused: h = [relu](mean @ Wl + xin @ Wr + b) then row l2-normalize; bf16 out.
// one wave handles one 16-row tile, all 128 output cols.
__global__ __launch_bounds__(256) void k_gemm(const unsigned short* __restrict__ meanbf,
                                              const unsigned short* __restrict__ xin,
                                              const unsigned short* __restrict__ wfragL,
                                              const unsigned short* __restrict__ wfragR,
                                              const float* __restrict__ bias,
                                              unsigned short* __restrict__ outbf,
                                              int relu) {
  __shared__ __align__(16) unsigned short wl[8 * 4 * 64 * 8];  // 32 KB
  __shared__ __align__(16) unsigned short wr[8 * 4 * 64 * 8];  // 32 KB
  const int tid = threadIdx.x;
  {
    const uint4* gl = (const uint4*)wfragL;
    const uint4* gr = (const uint4*)wfragR;
    uint4* sl = (uint4*)wl;
    uint4* sr = (uint4*)wr;
    #pragma unroll
    for (int i = 0; i < 8; ++i) {  // 2048 uint4 per array / 256 threads
      sl[tid + 256 * i] = gl[tid + 256 * i];
      sr[tid + 256 * i] = gr[tid + 256 * i];
    }
  }
  __syncthreads();

  int wave = tid >> 6;
  int lane = tid & 63;
  int tb = blockIdx.x * 4 + wave;
  if (tb >= NTILES) return;

  int lg = lane >> 4;   // 0..3
  int li = lane & 15;   // 0..15

  // A fragments: lane holds row (tb*16+li), k = 32*kk + 8*lg + j (contiguous 16B)
  short8 am[4], ax[4];
  const unsigned short* mrow = meanbf + ((size_t)(tb * 16 + li)) * DIM + lg * 8;
  const unsigned short* xrow = xin + ((size_t)(tb * 16 + li)) * DIM + lg * 8;
  #pragma unroll
  for (int kk = 0; kk < 4; ++kk) {
    am[kk] = *(const short8*)(mrow + kk * 32);
    ax[kk] = *(const short8*)(xrow + kk * 32);
  }

  f32x4 acc[8];
  #pragma unroll
  for (int t = 0; t < 8; ++t) {
    f32x4 c = {0.f, 0.f, 0.f, 0.f};
    #pragma unroll
    for (int kk = 0; kk < 4; ++kk) {
      short8 bl = *(const short8*)(wl + (((t * 4 + kk) * 64 + lane) * 8));
      c = __builtin_amdgcn_mfma_f32_16x16x32_bf16(am[kk], bl, c, 0, 0, 0);
      short8 br = *(const short8*)(wr + (((t * 4 + kk) * 64 + lane) * 8));
      c = __builtin_amdgcn_mfma_f32_16x16x32_bf16(ax[kk], br, c, 0, 0, 0);
    }
    float bv = bias[t * 16 + li];
    #pragma unroll
    for (int r = 0; r < 4; ++r) {
      float v = c[r] + bv;
      if (relu) v = fmaxf(v, 0.f);
      c[r] = v;
    }
    acc[t] = c;
  }

  // l2 norm per output row: row = tb*16 + lg*4 + r; cols spread over t and li.
  float scale[4];
  #pragma unroll
  for (int r = 0; r < 4; ++r) {
    float s = 0.f;
    #pragma unroll
    for (int t = 0; t < 8; ++t) s += acc[t][r] * acc[t][r];
    s += __shfl_xor(s, 1);
    s += __shfl_xor(s, 2);
    s += __shfl_xor(s, 4);
    s += __shfl_xor(s, 8);
    float n = sqrtf(s);
    scale[r] = 1.0f / fmaxf(n, 1e-12f);
  }

  #pragma unroll
  for (int t = 0; t < 8; ++t) {
    #pragma unroll
    for (int r = 0; r < 4; ++r) {
      outbf[((size_t)(tb * 16 + lg * 4 + r)) * DIM + t * 16 + li] =
          f2bf(acc[t][r] * scale[r]);
    }
  }
}

// ---------------- pooling ----------------

__global__ void k_pool(const unsigned short* __restrict__ h,
                       const int* __restrict__ batch, float* __restrict__ out) {
  int c = threadIdx.x;  // 0..127
  int n0 = blockIdx.x * 128;
  int nend = n0 + 128;
  if (nend > N_NODES) nend = N_NODES;
  float acc = 0.f;
  int cur = batch[n0];
  for (int n = n0; n < nend; ++n) {
    int g = batch[n];
    if (g != cur) {
      atomicAdd(&out[cur * DIM + c], acc);
      acc = 0.f;
      cur = g;
    }
    acc += bf2f(h[(size_t)n * DIM + c]);
  }
  atomicAdd(&out[cur * DIM + c], acc);
}

__global__ void k_div(float* __restrict__ out, const int* __restrict__ gcnt) {
  int i = blockIdx.x * 128 + threadIdx.x;  // 8192
  int g = i >> 7;
  int cv = gcnt[g];
  out[i] = out[i] / (float)(cv > 1 ? cv : 1);
}

// ---------------- launch ----------------

extern "C" void kernel_launch(void* const* d_in, const int* in_sizes, int n_in,
                              void* d_out, int out_size, void* d_ws, size_t ws_size,
                              hipStream_t stream) {
  const float* x   = (const float*)d_in[0];
  const int* ei    = (const int*)d_in[1];
  const int* batch = (const int*)d_in[2];
  const float* Wl1 = (const float*)d_in[3];
  const float* Wr1 = (const float*)d_in[4];
  const float* b1  = (const float*)d_in[5];
  const float* Wl2 = (const float*)d_in[6];
  const float* Wr2 = (const float*)d_in[7];
  const float* b2  = (const float*)d_in[8];
  const float* Wl3 = (const float*)d_in[9];
  const float* Wr3 = (const float*)d_in[10];
  const float* b3  = (const float*)d_in[11];
  float* out = (float*)d_out;

  char* ws = (char*)d_ws;
  size_t off = 0;
  auto alloc = [&](size_t bytes) {
    void* p = ws + off;
    off += (bytes + 255) & ~(size_t)255;
    return p;
  };
  unsigned short* xbf   = (unsigned short*)alloc((size_t)N_NODES * DIM * 2);
  unsigned short* hB    = (unsigned short*)alloc((size_t)N_NODES * DIM * 2);
  unsigned short* hC    = (unsigned short*)alloc((size_t)N_NODES * DIM * 2);
  unsigned short* mean  = (unsigned short*)alloc((size_t)N_NODES * DIM * 2);
  unsigned short* wfrag = (unsigned short*)alloc((size_t)6 * 2048 * 16);
  int* deg    = (int*)alloc((size_t)N_NODES * 4);
  int* rowptr = (int*)alloc((size_t)(N_NODES + 1) * 4);
  int* wofs   = (int*)alloc((size_t)N_NODES * 4);
  int* col    = (int*)alloc((size_t)N_EDGES * 4);
  int* gcnt   = (int*)alloc((size_t)N_GRAPHS * 4);

  // prep
  k_zero<<<196, 256, 0, stream>>>(deg, out);
  k_deg<<<3125, 256, 0, stream>>>(ei, deg);
  k_scan<<<1, 256, 0, stream>>>(deg, rowptr, wofs);
  k_scatter<<<3125, 256, 0, stream>>>(ei, wofs, col);
  k_xbf<<<6250, 256, 0, stream>>>(x, xbf);
  k_wprep<<<48, 256, 0, stream>>>(Wl1, Wr1, Wl2, Wr2, Wl3, Wr3, wfrag);
  k_gcnt<<<1, 64, 0, stream>>>(batch, gcnt);

  // layer 1
  k_agg<<<12500, 256, 0, stream>>>(xbf, rowptr, col, mean);
  k_gemm<<<782, 256, 0, stream>>>(mean, xbf, wfrag + 0 * 16384, wfrag + 1 * 16384, b1, hB, 1);
  // layer 2
  k_agg<<<12500, 256, 0, stream>>>(hB, rowptr, col, mean);
  k_gemm<<<782, 256, 0, stream>>>(mean, hB, wfrag + 2 * 16384, wfrag + 3 * 16384, b2, hC, 1);
  // layer 3
  k_agg<<<12500, 256, 0, stream>>>(hC, rowptr, col, mean);
  k_gemm<<<782, 256, 0, stream>>>(mean, hC, wfrag + 4 * 16384, wfrag + 5 * 16384, b3, hB, 0);

  // global mean pool
  k_pool<<<391, 128, 0, stream>>>(hB, batch, out);
  k_div<<<64, 128, 0, stream>>>(out, gcnt);
}

// Round 3
// 284.655 us; speedup vs baseline: 2.2546x; 1.4575x over previous
//
#include <hip/hip_runtime.h>

#define N_NODES 50000
#define N_EDGES 800000
#define DIM 128
#define N_GRAPHS 64
#define NTILES 3125   // N_NODES / 16
#define NSB 196       // ceil(N_NODES/256)

typedef __attribute__((ext_vector_type(8))) short short8;
typedef __attribute__((ext_vector_type(4))) float f32x4;

__device__ __forceinline__ float bf2f(unsigned short h) {
  unsigned int u = ((unsigned int)h) << 16;
  return __builtin_bit_cast(float, u);
}
__device__ __forceinline__ unsigned short f2bf(float f) {
  unsigned int u = __builtin_bit_cast(unsigned int, f);
  u += 0x7FFFu + ((u >> 16) & 1u);
  return (unsigned short)(u >> 16);
}

// ---------------- prep kernels ----------------

__global__ void k_zero(int* deg, float* out) {
  int i = blockIdx.x * 256 + threadIdx.x;
  if (i < N_NODES) deg[i] = 0;
  if (i < N_GRAPHS * DIM) out[i] = 0.f;
}

__global__ void k_deg(const int* __restrict__ ei, int* __restrict__ deg) {
  int e = blockIdx.x * 256 + threadIdx.x;
  if (e >= N_EDGES) return;
  atomicAdd(&deg[ei[N_EDGES + e]], 1);
}

// hierarchical scan: (a) per-block sums, (b) scan of block sums, (c) per-block
// exclusive scan + block offset -> rowptr/wofs.
__global__ void k_scan_a(const int* __restrict__ deg, int* __restrict__ bsum) {
  int tid = threadIdx.x;
  int i = blockIdx.x * 256 + tid;
  int v = (i < N_NODES) ? deg[i] : 0;
  #pragma unroll
  for (int o = 32; o; o >>= 1) v += __shfl_down(v, o);
  __shared__ int ws[4];
  if ((tid & 63) == 0) ws[tid >> 6] = v;
  __syncthreads();
  if (tid == 0) bsum[blockIdx.x] = ws[0] + ws[1] + ws[2] + ws[3];
}

__global__ void k_scan_b(const int* __restrict__ bsum, int* __restrict__ boff) {
  __shared__ int s[256];
  int tid = threadIdx.x;
  int v = (tid < NSB) ? bsum[tid] : 0;
  s[tid] = v;
  __syncthreads();
  for (int off = 1; off < 256; off <<= 1) {
    int t = (tid >= off) ? s[tid - off] : 0;
    __syncthreads();
    s[tid] += t;
    __syncthreads();
  }
  if (tid < NSB) boff[tid] = s[tid] - v;  // exclusive
}

__global__ void k_scan_c(const int* __restrict__ deg, const int* __restrict__ boff,
                         int* __restrict__ rowptr, int* __restrict__ wofs) {
  __shared__ int s[256];
  int tid = threadIdx.x;
  int i = blockIdx.x * 256 + tid;
  int v = (i < N_NODES) ? deg[i] : 0;
  s[tid] = v;
  __syncthreads();
  for (int off = 1; off < 256; off <<= 1) {
    int t = (tid >= off) ? s[tid - off] : 0;
    __syncthreads();
    s[tid] += t;
    __syncthreads();
  }
  int excl = s[tid] - v + boff[blockIdx.x];
  if (i < N_NODES) {
    rowptr[i] = excl;
    wofs[i] = excl;
  }
  if (i == N_NODES - 1) rowptr[N_NODES] = excl + v;
}

__global__ void k_scatter(const int* __restrict__ ei, int* __restrict__ wofs,
                          int* __restrict__ col) {
  int e = blockIdx.x * 256 + threadIdx.x;
  if (e >= N_EDGES) return;
  int d = ei[N_EDGES + e];
  int p = atomicAdd(&wofs[d], 1);
  col[p] = ei[e];  // src node id
}

__global__ void k_xbf(const float* __restrict__ x, unsigned short* __restrict__ xbf) {
  int i = blockIdx.x * 256 + threadIdx.x;  // one float4 per thread
  if (i * 4 >= N_NODES * DIM) return;
  float4 v = ((const float4*)x)[i];
  unsigned int lo = (unsigned int)f2bf(v.x) | ((unsigned int)f2bf(v.y) << 16);
  unsigned int hi = (unsigned int)f2bf(v.z) | ((unsigned int)f2bf(v.w) << 16);
  uint2 o; o.x = lo; o.y = hi;
  ((uint2*)xbf)[i] = o;
}

// Fragment-ordered transposed bf16 weights: wfrag[mat][t][kk][lane][j]
// holds W[k0+j][16t + (lane&15)] with k0 = 32*kk + 8*(lane>>4).
__global__ void k_wprep(const float* __restrict__ w0, const float* __restrict__ w1,
                        const float* __restrict__ w2, const float* __restrict__ w3,
                        const float* __restrict__ w4, const float* __restrict__ w5,
                        unsigned short* __restrict__ wfrag) {
  int idx = blockIdx.x * 256 + threadIdx.x;  // 6 * 2048
  if (idx >= 6 * 2048) return;
  int mat = idx >> 11;
  int rem = idx & 2047;
  int lane = rem & 63;
  int kk = (rem >> 6) & 3;
  int t = rem >> 8;
  const float* w = (mat == 0) ? w0 : (mat == 1) ? w1 : (mat == 2) ? w2
                 : (mat == 3) ? w3 : (mat == 4) ? w4 : w5;
  int row = t * 16 + (lane & 15);          // output column c
  int k0 = kk * 32 + (lane >> 4) * 8;
  unsigned int v[8];
  #pragma unroll
  for (int j = 0; j < 8; ++j) v[j] = f2bf(w[(k0 + j) * DIM + row]);
  uint4 o;
  o.x = v[0] | (v[1] << 16);
  o.y = v[2] | (v[3] << 16);
  o.z = v[4] | (v[5] << 16);
  o.w = v[6] | (v[7] << 16);
  ((uint4*)wfrag)[idx] = o;
}

// batch is sorted: gcnt[g] = lower_bound(g+1) - lower_bound(g). No atomics.
__global__ void k_gcnt(const int* __restrict__ batch, int* __restrict__ gcnt) {
  int g = threadIdx.x;  // 0..63
  if (g >= N_GRAPHS) return;
  int lo = 0, hi = N_NODES;
  while (lo < hi) { int mid = (lo + hi) >> 1; if (batch[mid] < g) lo = mid + 1; else hi = mid; }
  int s = lo;
  lo = 0; hi = N_NODES;
  int g1 = g + 1;
  while (lo < hi) { int mid = (lo + hi) >> 1; if (batch[mid] < g1) lo = mid + 1; else hi = mid; }
  gcnt[g] = lo - s;
}

// ---------------- per-layer kernels ----------------

// one wave per node: mean over neighbor rows (bf16 in, f32 acc, bf16 out)
__global__ __launch_bounds__(256) void k_agg(const unsigned short* __restrict__ xin,
                                             const int* __restrict__ rowptr,
                                             const int* __restrict__ col,
                                             unsigned short* __restrict__ meanbf) {
  int wid = (blockIdx.x * blockDim.x + threadIdx.x) >> 6;
  int lane = threadIdx.x & 63;
  if (wid >= N_NODES) return;
  int start = rowptr[wid], end = rowptr[wid + 1];
  float a0 = 0.f, a1 = 0.f;
  for (int j0 = start; j0 < end; j0 += 64) {
    int m = end - j0;
    if (m > 64) m = 64;
    int idx = (lane < m) ? col[j0 + lane] : 0;
    int jj = 0;
    for (; jj + 4 <= m; jj += 4) {
      int s0 = __shfl(idx, jj + 0);
      int s1 = __shfl(idx, jj + 1);
      int s2 = __shfl(idx, jj + 2);
      int s3 = __shfl(idx, jj + 3);
      unsigned int v0 = *(const unsigned int*)(xin + (size_t)s0 * DIM + lane * 2);
      unsigned int v1 = *(const unsigned int*)(xin + (size_t)s1 * DIM + lane * 2);
      unsigned int v2 = *(const unsigned int*)(xin + (size_t)s2 * DIM + lane * 2);
      unsigned int v3 = *(const unsigned int*)(xin + (size_t)s3 * DIM + lane * 2);
      a0 += bf2f((unsigned short)(v0 & 0xffff)) + bf2f((unsigned short)(v1 & 0xffff))
          + bf2f((unsigned short)(v2 & 0xffff)) + bf2f((unsigned short)(v3 & 0xffff));
      a1 += bf2f((unsigned short)(v0 >> 16)) + bf2f((unsigned short)(v1 >> 16))
          + bf2f((unsigned short)(v2 >> 16)) + bf2f((unsigned short)(v3 >> 16));
    }
    for (; jj < m; ++jj) {
      int s = __shfl(idx, jj);
      unsigned int v = *(const unsigned int*)(xin + (size_t)s * DIM + lane * 2);
      a0 += bf2f((unsigned short)(v & 0xffff));
      a1 += bf2f((unsigned short)(v >> 16));
    }
  }
  int d = end - start;
  float sc = 1.0f / (float)(d > 1 ? d : 1);
  unsigned int o = (unsigned int)f2bf(a0 * sc) | ((unsigned int)f2bf(a1 * sc) << 16);
  *(unsigned int*)(meanbf + (size_t)wid * DIM + lane * 2) = o;
}

// fused: h = [relu](mean @ Wl + xin @ Wr + b) then row l2-normalize; bf16 out.
// one wave handles one 16-row tile, all 128 output cols.
__global__ __launch_bounds__(256) void k_gemm(const unsigned short* __restrict__ meanbf,
                                              const unsigned short* __restrict__ xin,
                                              const unsigned short* __restrict__ wfragL,
                                              const unsigned short* __restrict__ wfragR,
                                              const float* __restrict__ bias,
                                              unsigned short* __restrict__ outbf,
                                              int relu) {
  __shared__ __align__(16) unsigned short wl[8 * 4 * 64 * 8];  // 32 KB
  __shared__ __align__(16) unsigned short wr[8 * 4 * 64 * 8];  // 32 KB
  const int tid = threadIdx.x;
  {
    const uint4* gl = (const uint4*)wfragL;
    const uint4* gr = (const uint4*)wfragR;
    uint4* sl = (uint4*)wl;
    uint4* sr = (uint4*)wr;
    #pragma unroll
    for (int i = 0; i < 8; ++i) {  // 2048 uint4 per array / 256 threads
      sl[tid + 256 * i] = gl[tid + 256 * i];
      sr[tid + 256 * i] = gr[tid + 256 * i];
    }
  }
  __syncthreads();

  int wave = tid >> 6;
  int lane = tid & 63;
  int tb = blockIdx.x * 4 + wave;
  if (tb >= NTILES) return;

  int lg = lane >> 4;   // 0..3
  int li = lane & 15;   // 0..15

  // A fragments: lane holds row (tb*16+li), k = 32*kk + 8*lg + j (contiguous 16B)
  short8 am[4], ax[4];
  const unsigned short* mrow = meanbf + ((size_t)(tb * 16 + li)) * DIM + lg * 8;
  const unsigned short* xrow = xin + ((size_t)(tb * 16 + li)) * DIM + lg * 8;
  #pragma unroll
  for (int kk = 0; kk < 4; ++kk) {
    am[kk] = *(const short8*)(mrow + kk * 32);
    ax[kk] = *(const short8*)(xrow + kk * 32);
  }

  f32x4 acc[8];
  #pragma unroll
  for (int t = 0; t < 8; ++t) {
    f32x4 c = {0.f, 0.f, 0.f, 0.f};
    #pragma unroll
    for (int kk = 0; kk < 4; ++kk) {
      short8 bl = *(const short8*)(wl + (((t * 4 + kk) * 64 + lane) * 8));
      c = __builtin_amdgcn_mfma_f32_16x16x32_bf16(am[kk], bl, c, 0, 0, 0);
      short8 br = *(const short8*)(wr + (((t * 4 + kk) * 64 + lane) * 8));
      c = __builtin_amdgcn_mfma_f32_16x16x32_bf16(ax[kk], br, c, 0, 0, 0);
    }
    float bv = bias[t * 16 + li];
    #pragma unroll
    for (int r = 0; r < 4; ++r) {
      float v = c[r] + bv;
      if (relu) v = fmaxf(v, 0.f);
      c[r] = v;
    }
    acc[t] = c;
  }

  // l2 norm per output row: row = tb*16 + lg*4 + r; cols spread over t and li.
  float scale[4];
  #pragma unroll
  for (int r = 0; r < 4; ++r) {
    float s = 0.f;
    #pragma unroll
    for (int t = 0; t < 8; ++t) s += acc[t][r] * acc[t][r];
    s += __shfl_xor(s, 1);
    s += __shfl_xor(s, 2);
    s += __shfl_xor(s, 4);
    s += __shfl_xor(s, 8);
    float n = sqrtf(s);
    scale[r] = 1.0f / fmaxf(n, 1e-12f);
  }

  #pragma unroll
  for (int t = 0; t < 8; ++t) {
    #pragma unroll
    for (int r = 0; r < 4; ++r) {
      outbf[((size_t)(tb * 16 + lg * 4 + r)) * DIM + t * 16 + li] =
          f2bf(acc[t][r] * scale[r]);
    }
  }
}

// ---------------- pooling ----------------

__global__ void k_pool(const unsigned short* __restrict__ h,
                       const int* __restrict__ batch, float* __restrict__ out) {
  int c = threadIdx.x;  // 0..127
  int n0 = blockIdx.x * 128;
  int nend = n0 + 128;
  if (nend > N_NODES) nend = N_NODES;
  float acc = 0.f;
  int cur = batch[n0];
  for (int n = n0; n < nend; ++n) {
    int g = batch[n];
    if (g != cur) {
      atomicAdd(&out[cur * DIM + c], acc);
      acc = 0.f;
      cur = g;
    }
    acc += bf2f(h[(size_t)n * DIM + c]);
  }
  atomicAdd(&out[cur * DIM + c], acc);
}

__global__ void k_div(float* __restrict__ out, const int* __restrict__ gcnt) {
  int i = blockIdx.x * 128 + threadIdx.x;  // 8192
  int g = i >> 7;
  int cv = gcnt[g];
  out[i] = out[i] / (float)(cv > 1 ? cv : 1);
}

// ---------------- launch ----------------

extern "C" void kernel_launch(void* const* d_in, const int* in_sizes, int n_in,
                              void* d_out, int out_size, void* d_ws, size_t ws_size,
                              hipStream_t stream) {
  const float* x   = (const float*)d_in[0];
  const int* ei    = (const int*)d_in[1];
  const int* batch = (const int*)d_in[2];
  const float* Wl1 = (const float*)d_in[3];
  const float* Wr1 = (const float*)d_in[4];
  const float* b1  = (const float*)d_in[5];
  const float* Wl2 = (const float*)d_in[6];
  const float* Wr2 = (const float*)d_in[7];
  const float* b2  = (const float*)d_in[8];
  const float* Wl3 = (const float*)d_in[9];
  const float* Wr3 = (const float*)d_in[10];
  const float* b3  = (const float*)d_in[11];
  float* out = (float*)d_out;

  char* ws = (char*)d_ws;
  size_t off = 0;
  auto alloc = [&](size_t bytes) {
    void* p = ws + off;
    off += (bytes + 255) & ~(size_t)255;
    return p;
  };
  unsigned short* xbf   = (unsigned short*)alloc((size_t)N_NODES * DIM * 2);
  unsigned short* hB    = (unsigned short*)alloc((size_t)N_NODES * DIM * 2);
  unsigned short* hC    = (unsigned short*)alloc((size_t)N_NODES * DIM * 2);
  unsigned short* mean  = (unsigned short*)alloc((size_t)N_NODES * DIM * 2);
  unsigned short* wfrag = (unsigned short*)alloc((size_t)6 * 2048 * 16);
  int* deg    = (int*)alloc((size_t)N_NODES * 4);
  int* rowptr = (int*)alloc((size_t)(N_NODES + 1) * 4);
  int* wofs   = (int*)alloc((size_t)N_NODES * 4);
  int* col    = (int*)alloc((size_t)N_EDGES * 4);
  int* gcnt   = (int*)alloc((size_t)N_GRAPHS * 4);
  int* bsum   = (int*)alloc((size_t)NSB * 4);
  int* boff   = (int*)alloc((size_t)NSB * 4);

  // prep
  k_zero<<<196, 256, 0, stream>>>(deg, out);
  k_deg<<<3125, 256, 0, stream>>>(ei, deg);
  k_scan_a<<<NSB, 256, 0, stream>>>(deg, bsum);
  k_scan_b<<<1, 256, 0, stream>>>(bsum, boff);
  k_scan_c<<<NSB, 256, 0, stream>>>(deg, boff, rowptr, wofs);
  k_scatter<<<3125, 256, 0, stream>>>(ei, wofs, col);
  k_xbf<<<6250, 256, 0, stream>>>(x, xbf);
  k_wprep<<<48, 256, 0, stream>>>(Wl1, Wr1, Wl2, Wr2, Wl3, Wr3, wfrag);
  k_gcnt<<<1, 64, 0, stream>>>(batch, gcnt);

  // layer 1
  k_agg<<<12500, 256, 0, stream>>>(xbf, rowptr, col, mean);
  k_gemm<<<782, 256, 0, stream>>>(mean, xbf, wfrag + 0 * 16384, wfrag + 1 * 16384, b1, hB, 1);
  // layer 2
  k_agg<<<12500, 256, 0, stream>>>(hB, rowptr, col, mean);
  k_gemm<<<782, 256, 0, stream>>>(mean, hB, wfrag + 2 * 16384, wfrag + 3 * 16384, b2, hC, 1);
  // layer 3
  k_agg<<<12500, 256, 0, stream>>>(hC, rowptr, col, mean);
  k_gemm<<<782, 256, 0, stream>>>(mean, hC, wfrag + 4 * 16384, wfrag + 5 * 16384, b3, hB, 0);

  // global mean pool
  k_pool<<<391, 128, 0, stream>>>(hB, batch, out);
  k_div<<<64, 128, 0, stream>>>(out, gcnt);
}

// Round 4
// 228.779 us; speedup vs baseline: 2.8053x; 1.2442x over previous
//
#include <hip/hip_runtime.h>

#define N_NODES 50000
#define N_EDGES 800000
#define DIM 128
#define N_GRAPHS 64
#define NTILES 3125   // N_NODES / 16
#define NB 196        // buckets of 256 nodes: ceil(50000/256)
#define GPART 256     // partition blocks for bucketing
#define EPB 3125      // N_EDGES / GPART (exact)

typedef __attribute__((ext_vector_type(8))) short short8;
typedef __attribute__((ext_vector_type(4))) float f32x4;

__device__ __forceinline__ float bf2f(unsigned short h) {
  unsigned int u = ((unsigned int)h) << 16;
  return __builtin_bit_cast(float, u);
}
__device__ __forceinline__ unsigned short f2bf(float f) {
  unsigned int u = __builtin_bit_cast(unsigned int, f);
  u += 0x7FFFu + ((u >> 16) & 1u);
  return (unsigned short)(u >> 16);
}

// ---------------- CSR build (bucketed counting sort, no global atomics) ----

__global__ void k_zero(float* out) {
  int i = blockIdx.x * 256 + threadIdx.x;
  if (i < N_GRAPHS * DIM) out[i] = 0.f;
}

// per-partition-block histogram over NB buckets
__global__ __launch_bounds__(256) void k_hist(const int* __restrict__ ei,
                                              int* __restrict__ cnt) {
  __shared__ int h[NB];
  int t = threadIdx.x, g = blockIdx.x;
  if (t < NB) h[t] = 0;
  __syncthreads();
  int e0 = g * EPB;
  for (int i = t; i < EPB; i += 256) {
    int dst = ei[N_EDGES + e0 + i];
    atomicAdd(&h[dst >> 8], 1);
  }
  __syncthreads();
  if (t < NB) cnt[g * NB + t] = h[t];
}

// column-prefix over g + bucket-base scan; rewrites cnt[g][b] -> global base
__global__ void k_escan(int* __restrict__ cnt, int* __restrict__ bb) {
  __shared__ int s[256];
  int t = threadIdx.x;
  int tot = 0;
  if (t < NB)
    for (int g = 0; g < GPART; ++g) tot += cnt[g * NB + t];
  s[t] = (t < NB) ? tot : 0;
  __syncthreads();
  for (int off = 1; off < 256; off <<= 1) {
    int v = (t >= off) ? s[t - off] : 0;
    __syncthreads();
    s[t] += v;
    __syncthreads();
  }
  if (t < NB) {
    int excl = s[t] - tot;
    bb[t] = excl;
    if (t == NB - 1) bb[NB] = s[t];  // == N_EDGES
    int run = excl;
    for (int g = 0; g < GPART; ++g) {
      int c = cnt[g * NB + t];
      cnt[g * NB + t] = run;
      run += c;
    }
  }
}

// scatter edges into reserved contiguous ranges (dense writes)
__global__ __launch_bounds__(256) void k_bucket(const int* __restrict__ ei,
                                                const int* __restrict__ cnt,
                                                unsigned int* __restrict__ bucketed) {
  __shared__ int lofs[NB];
  int t = threadIdx.x, g = blockIdx.x;
  if (t < NB) lofs[t] = cnt[g * NB + t];
  __syncthreads();
  int e0 = g * EPB;
  for (int i = t; i < EPB; i += 256) {
    int src = ei[e0 + i];
    int dst = ei[N_EDGES + e0 + i];
    int p = atomicAdd(&lofs[dst >> 8], 1);
    bucketed[p] = (unsigned int)src | ((unsigned int)(dst & 255) << 16);
  }
}

// per-bucket: local hist -> scan -> rowptr (coalesced) + col scatter (L1-local)
__global__ __launch_bounds__(256) void k_finalize(const unsigned int* __restrict__ bucketed,
                                                  const int* __restrict__ bb,
                                                  int* __restrict__ rowptr,
                                                  int* __restrict__ col) {
  __shared__ int h[256], s[256], c[256];
  int t = threadIdx.x, b = blockIdx.x;
  int s0 = bb[b], s1 = bb[b + 1];
  int n = s1 - s0;
  h[t] = 0;
  __syncthreads();
  for (int i = t; i < n; i += 256) atomicAdd(&h[bucketed[s0 + i] >> 16], 1);
  __syncthreads();
  s[t] = h[t];
  __syncthreads();
  for (int off = 1; off < 256; off <<= 1) {
    int v = (t >= off) ? s[t - off] : 0;
    __syncthreads();
    s[t] += v;
    __syncthreads();
  }
  int excl = s[t] - h[t];
  int node = b * 256 + t;
  if (node < N_NODES) rowptr[node] = s0 + excl;
  if (b == NB - 1 && t == 255) rowptr[N_NODES] = N_EDGES;
  c[t] = s0 + excl;
  __syncthreads();
  for (int i = t; i < n; i += 256) {
    unsigned int v = bucketed[s0 + i];
    int p = atomicAdd(&c[v >> 16], 1);
    col[p] = (int)(v & 0xffffu);
  }
}

// ---------------- prep kernels ----------------

__global__ void k_xbf(const float* __restrict__ x, unsigned short* __restrict__ xbf) {
  int i = blockIdx.x * 256 + threadIdx.x;  // one float4 per thread
  if (i * 4 >= N_NODES * DIM) return;
  float4 v = ((const float4*)x)[i];
  unsigned int lo = (unsigned int)f2bf(v.x) | ((unsigned int)f2bf(v.y) << 16);
  unsigned int hi = (unsigned int)f2bf(v.z) | ((unsigned int)f2bf(v.w) << 16);
  uint2 o; o.x = lo; o.y = hi;
  ((uint2*)xbf)[i] = o;
}

// Fragment-ordered transposed bf16 weights: wfrag[mat][t][kk][lane][j]
// holds W[k0+j][16t + (lane&15)] with k0 = 32*kk + 8*(lane>>4).
__global__ void k_wprep(const float* __restrict__ w0, const float* __restrict__ w1,
                        const float* __restrict__ w2, const float* __restrict__ w3,
                        const float* __restrict__ w4, const float* __restrict__ w5,
                        unsigned short* __restrict__ wfrag) {
  int idx = blockIdx.x * 256 + threadIdx.x;  // 6 * 2048
  if (idx >= 6 * 2048) return;
  int mat = idx >> 11;
  int rem = idx & 2047;
  int lane = rem & 63;
  int kk = (rem >> 6) & 3;
  int t = rem >> 8;
  const float* w = (mat == 0) ? w0 : (mat == 1) ? w1 : (mat == 2) ? w2
                 : (mat == 3) ? w3 : (mat == 4) ? w4 : w5;
  int row = t * 16 + (lane & 15);          // output column c
  int k0 = kk * 32 + (lane >> 4) * 8;
  unsigned int v[8];
  #pragma unroll
  for (int j = 0; j < 8; ++j) v[j] = f2bf(w[(k0 + j) * DIM + row]);
  uint4 o;
  o.x = v[0] | (v[1] << 16);
  o.y = v[2] | (v[3] << 16);
  o.z = v[4] | (v[5] << 16);
  o.w = v[6] | (v[7] << 16);
  ((uint4*)wfrag)[idx] = o;
}

// batch is sorted: gcnt[g] = lower_bound(g+1) - lower_bound(g). No atomics.
__global__ void k_gcnt(const int* __restrict__ batch, int* __restrict__ gcnt) {
  int g = threadIdx.x;  // 0..63
  if (g >= N_GRAPHS) return;
  int lo = 0, hi = N_NODES;
  while (lo < hi) { int mid = (lo + hi) >> 1; if (batch[mid] < g) lo = mid + 1; else hi = mid; }
  int s = lo;
  lo = 0; hi = N_NODES;
  int g1 = g + 1;
  while (lo < hi) { int mid = (lo + hi) >> 1; if (batch[mid] < g1) lo = mid + 1; else hi = mid; }
  gcnt[g] = lo - s;
}

// ---------------- per-layer kernels ----------------

// one wave per node: mean over neighbor rows (bf16 in, f32 acc, bf16 out)
__global__ __launch_bounds__(256) void k_agg(const unsigned short* __restrict__ xin,
                                             const int* __restrict__ rowptr,
                                             const int* __restrict__ col,
                                             unsigned short* __restrict__ meanbf) {
  int wid = (blockIdx.x * blockDim.x + threadIdx.x) >> 6;
  int lane = threadIdx.x & 63;
  if (wid >= N_NODES) return;
  int start = rowptr[wid], end = rowptr[wid + 1];
  float a0 = 0.f, a1 = 0.f;
  for (int j0 = start; j0 < end; j0 += 64) {
    int m = end - j0;
    if (m > 64) m = 64;
    int idx = (lane < m) ? col[j0 + lane] : 0;
    int jj = 0;
    for (; jj + 4 <= m; jj += 4) {
      int s0 = __shfl(idx, jj + 0);
      int s1 = __shfl(idx, jj + 1);
      int s2 = __shfl(idx, jj + 2);
      int s3 = __shfl(idx, jj + 3);
      unsigned int v0 = *(const unsigned int*)(xin + (size_t)s0 * DIM + lane * 2);
      unsigned int v1 = *(const unsigned int*)(xin + (size_t)s1 * DIM + lane * 2);
      unsigned int v2 = *(const unsigned int*)(xin + (size_t)s2 * DIM + lane * 2);
      unsigned int v3 = *(const unsigned int*)(xin + (size_t)s3 * DIM + lane * 2);
      a0 += bf2f((unsigned short)(v0 & 0xffff)) + bf2f((unsigned short)(v1 & 0xffff))
          + bf2f((unsigned short)(v2 & 0xffff)) + bf2f((unsigned short)(v3 & 0xffff));
      a1 += bf2f((unsigned short)(v0 >> 16)) + bf2f((unsigned short)(v1 >> 16))
          + bf2f((unsigned short)(v2 >> 16)) + bf2f((unsigned short)(v3 >> 16));
    }
    for (; jj < m; ++jj) {
      int s = __shfl(idx, jj);
      unsigned int v = *(const unsigned int*)(xin + (size_t)s * DIM + lane * 2);
      a0 += bf2f((unsigned short)(v & 0xffff));
      a1 += bf2f((unsigned short)(v >> 16));
    }
  }
  int d = end - start;
  float sc = 1.0f / (float)(d > 1 ? d : 1);
  unsigned int o = (unsigned int)f2bf(a0 * sc) | ((unsigned int)f2bf(a1 * sc) << 16);
  *(unsigned int*)(meanbf + (size_t)wid * DIM + lane * 2) = o;
}

// fused: h = [relu](mean @ Wl + xin @ Wr + b) then row l2-normalize; bf16 out.
// one wave handles one 16-row tile, all 128 output cols.
__global__ __launch_bounds__(256) void k_gemm(const unsigned short* __restrict__ meanbf,
                                              const unsigned short* __restrict__ xin,
                                              const unsigned short* __restrict__ wfragL,
                                              const unsigned short* __restrict__ wfragR,
                                              const float* __restrict__ bias,
                                              unsigned short* __restrict__ outbf,
                                              int relu) {
  __shared__ __align__(16) unsigned short wl[8 * 4 * 64 * 8];  // 32 KB
  __shared__ __align__(16) unsigned short wr[8 * 4 * 64 * 8];  // 32 KB
  const int tid = threadIdx.x;
  {
    const uint4* gl = (const uint4*)wfragL;
    const uint4* gr = (const uint4*)wfragR;
    uint4* sl = (uint4*)wl;
    uint4* sr = (uint4*)wr;
    #pragma unroll
    for (int i = 0; i < 8; ++i) {  // 2048 uint4 per array / 256 threads
      sl[tid + 256 * i] = gl[tid + 256 * i];
      sr[tid + 256 * i] = gr[tid + 256 * i];
    }
  }
  __syncthreads();

  int wave = tid >> 6;
  int lane = tid & 63;
  int tb = blockIdx.x * 4 + wave;
  if (tb >= NTILES) return;

  int lg = lane >> 4;   // 0..3
  int li = lane & 15;   // 0..15

  // A fragments: lane holds row (tb*16+li), k = 32*kk + 8*lg + j (contiguous 16B)
  short8 am[4], ax[4];
  const unsigned short* mrow = meanbf + ((size_t)(tb * 16 + li)) * DIM + lg * 8;
  const unsigned short* xrow = xin + ((size_t)(tb * 16 + li)) * DIM + lg * 8;
  #pragma unroll
  for (int kk = 0; kk < 4; ++kk) {
    am[kk] = *(const short8*)(mrow + kk * 32);
    ax[kk] = *(const short8*)(xrow + kk * 32);
  }

  f32x4 acc[8];
  #pragma unroll
  for (int t = 0; t < 8; ++t) {
    f32x4 c = {0.f, 0.f, 0.f, 0.f};
    #pragma unroll
    for (int kk = 0; kk < 4; ++kk) {
      short8 bl = *(const short8*)(wl + (((t * 4 + kk) * 64 + lane) * 8));
      c = __builtin_amdgcn_mfma_f32_16x16x32_bf16(am[kk], bl, c, 0, 0, 0);
      short8 br = *(const short8*)(wr + (((t * 4 + kk) * 64 + lane) * 8));
      c = __builtin_amdgcn_mfma_f32_16x16x32_bf16(ax[kk], br, c, 0, 0, 0);
    }
    float bv = bias[t * 16 + li];
    #pragma unroll
    for (int r = 0; r < 4; ++r) {
      float v = c[r] + bv;
      if (relu) v = fmaxf(v, 0.f);
      c[r] = v;
    }
    acc[t] = c;
  }

  // l2 norm per output row: row = tb*16 + lg*4 + r; cols spread over t and li.
  float scale[4];
  #pragma unroll
  for (int r = 0; r < 4; ++r) {
    float s = 0.f;
    #pragma unroll
    for (int t = 0; t < 8; ++t) s += acc[t][r] * acc[t][r];
    s += __shfl_xor(s, 1);
    s += __shfl_xor(s, 2);
    s += __shfl_xor(s, 4);
    s += __shfl_xor(s, 8);
    float n = sqrtf(s);
    scale[r] = 1.0f / fmaxf(n, 1e-12f);
  }

  #pragma unroll
  for (int t = 0; t < 8; ++t) {
    #pragma unroll
    for (int r = 0; r < 4; ++r) {
      outbf[((size_t)(tb * 16 + lg * 4 + r)) * DIM + t * 16 + li] =
          f2bf(acc[t][r] * scale[r]);
    }
  }
}

// ---------------- pooling ----------------

__global__ void k_pool(const unsigned short* __restrict__ h,
                       const int* __restrict__ batch, float* __restrict__ out) {
  int c = threadIdx.x;  // 0..127
  int n0 = blockIdx.x * 128;
  int nend = n0 + 128;
  if (nend > N_NODES) nend = N_NODES;
  float acc = 0.f;
  int cur = batch[n0];
  for (int n = n0; n < nend; ++n) {
    int g = batch[n];
    if (g != cur) {
      atomicAdd(&out[cur * DIM + c], acc);
      acc = 0.f;
      cur = g;
    }
    acc += bf2f(h[(size_t)n * DIM + c]);
  }
  atomicAdd(&out[cur * DIM + c], acc);
}

__global__ void k_div(float* __restrict__ out, const int* __restrict__ gcnt) {
  int i = blockIdx.x * 128 + threadIdx.x;  // 8192
  int g = i >> 7;
  int cv = gcnt[g];
  out[i] = out[i] / (float)(cv > 1 ? cv : 1);
}

// ---------------- launch ----------------

extern "C" void kernel_launch(void* const* d_in, const int* in_sizes, int n_in,
                              void* d_out, int out_size, void* d_ws, size_t ws_size,
                              hipStream_t stream) {
  const float* x   = (const float*)d_in[0];
  const int* ei    = (const int*)d_in[1];
  const int* batch = (const int*)d_in[2];
  const float* Wl1 = (const float*)d_in[3];
  const float* Wr1 = (const float*)d_in[4];
  const float* b1  = (const float*)d_in[5];
  const float* Wl2 = (const float*)d_in[6];
  const float* Wr2 = (const float*)d_in[7];
  const float* b2  = (const float*)d_in[8];
  const float* Wl3 = (const float*)d_in[9];
  const float* Wr3 = (const float*)d_in[10];
  const float* b3  = (const float*)d_in[11];
  float* out = (float*)d_out;

  char* ws = (char*)d_ws;
  size_t off = 0;
  auto alloc = [&](size_t bytes) {
    void* p = ws + off;
    off += (bytes + 255) & ~(size_t)255;
    return p;
  };
  unsigned short* xbf   = (unsigned short*)alloc((size_t)N_NODES * DIM * 2);
  unsigned short* hB    = (unsigned short*)alloc((size_t)N_NODES * DIM * 2);
  unsigned short* hC    = (unsigned short*)alloc((size_t)N_NODES * DIM * 2);
  unsigned short* mean  = (unsigned short*)alloc((size_t)N_NODES * DIM * 2);
  unsigned short* wfrag = (unsigned short*)alloc((size_t)6 * 2048 * 16);
  int* rowptr = (int*)alloc((size_t)(N_NODES + 1) * 4);
  int* col    = (int*)alloc((size_t)N_EDGES * 4);
  int* gcnt   = (int*)alloc((size_t)N_GRAPHS * 4);
  int* cnt    = (int*)alloc((size_t)GPART * NB * 4);
  int* bb     = (int*)alloc((size_t)(NB + 1) * 4);
  // bucketed (3.2 MB) aliases mean (12.8 MB): disjoint lifetime (CSR build
  // finishes before the first k_agg writes mean).
  unsigned int* bucketed = (unsigned int*)mean;

  // CSR build
  k_hist<<<GPART, 256, 0, stream>>>(ei, cnt);
  k_escan<<<1, 256, 0, stream>>>(cnt, bb);
  k_bucket<<<GPART, 256, 0, stream>>>(ei, cnt, bucketed);
  k_finalize<<<NB, 256, 0, stream>>>(bucketed, bb, rowptr, col);

  // prep (independent of CSR)
  k_zero<<<32, 256, 0, stream>>>(out);
  k_xbf<<<6250, 256, 0, stream>>>(x, xbf);
  k_wprep<<<48, 256, 0, stream>>>(Wl1, Wr1, Wl2, Wr2, Wl3, Wr3, wfrag);
  k_gcnt<<<1, 64, 0, stream>>>(batch, gcnt);

  // layer 1
  k_agg<<<12500, 256, 0, stream>>>(xbf, rowptr, col, mean);
  k_gemm<<<782, 256, 0, stream>>>(mean, xbf, wfrag + 0 * 16384, wfrag + 1 * 16384, b1, hB, 1);
  // layer 2
  k_agg<<<12500, 256, 0, stream>>>(hB, rowptr, col, mean);
  k_gemm<<<782, 256, 0, stream>>>(mean, hB, wfrag + 2 * 16384, wfrag + 3 * 16384, b2, hC, 1);
  // layer 3
  k_agg<<<12500, 256, 0, stream>>>(hC, rowptr, col, mean);
  k_gemm<<<782, 256, 0, stream>>>(mean, hC, wfrag + 4 * 16384, wfrag + 5 * 16384, b3, hB, 0);

  // global mean pool
  k_pool<<<391, 128, 0, stream>>>(hB, batch, out);
  k_div<<<64, 128, 0, stream>>>(out, gcnt);
}